// Round 11
// baseline (673.919 us; speedup 1.0000x reference)
//
#include <hip/hip_runtime.h>
#include <hip/hip_bf16.h>

#define N_NODES 100000
#define N_EDGES 1600000
#define IN_DIM 128
#define HID_DIM 256
#define LN_EPS 1e-5f
#define NT (N_NODES / 16)   // 6250 16-row tiles, exact

// histogram geometry
#define NCHUNK 32
#define CHUNK_E (N_EDGES / NCHUNK)     // 50000 edges/chunk (12500 int4, exact)
#define NSLICE 8
#define SLICE (N_NODES / NSLICE)       // 12500 nodes/slice (50 KB LDS bins)
#define HBLK (NCHUNK * NSLICE)         // 256 blocks per histogrammed array

#define EDGE_BLOCKS (N_EDGES / 256)       // 6250, exact
#define FCVT_BLOCKS (N_NODES * 32 / 256)  // 12500, exact

// fused gemm geometry: 256 persistent blocks (1/CU), 16 waves each
#define GEMM_BLOCKS 256
#define GEMM_WAVES (GEMM_BLOCKS * 16)   // 4096 global waves

typedef short bf16x8 __attribute__((ext_vector_type(8)));
typedef float f32x4  __attribute__((ext_vector_type(4)));

static __device__ __forceinline__ short f2bf(float x) {
    return __builtin_bit_cast(short, __float2bfloat16(x));  // RNE round
}

// ---------------------------------------------------------------------------
// Kernel 1: LDS-bin histograms — NO global atomics.
//   blocks [0, 256)   : histogram of src  -> p_out[chunk][node]
//   blocks [256, 512) : histogram of dst  -> p_in[chunk][node], and the LDS
//                       atomic's return value = within-chunk rank -> rank16[e]
// ---------------------------------------------------------------------------
__global__ __launch_bounds__(1024)
void hist_kernel(const int* __restrict__ src, const int* __restrict__ dst,
                 unsigned* __restrict__ p_out, unsigned* __restrict__ p_in,
                 ushort* __restrict__ rank16) {
    __shared__ unsigned bins[SLICE];   // 50 KB
    const int b = blockIdx.x;
    const bool isdst = (b >= HBLK);
    const int bb = isdst ? (b - HBLK) : b;
    const int ci = bb >> 3;            // chunk 0..31
    const int si = bb & 7;             // slice 0..7
    const int s0 = si * SLICE;

    for (int i = threadIdx.x; i < SLICE; i += 1024) bins[i] = 0;
    __syncthreads();

    const int4* ep4 = (const int4*)((isdst ? dst : src) + ci * CHUNK_E);
    if (isdst) {
        const int ebase = ci * CHUNK_E;
        for (int i = threadIdx.x; i < CHUNK_E / 4; i += 1024) {
            int4 v = ep4[i];
            int e0 = ebase + i * 4;
            unsigned u0 = (unsigned)(v.x - s0);
            unsigned u1 = (unsigned)(v.y - s0);
            unsigned u2 = (unsigned)(v.z - s0);
            unsigned u3 = (unsigned)(v.w - s0);
            if (u0 < SLICE) rank16[e0 + 0] = (ushort)atomicAdd(&bins[u0], 1u);
            if (u1 < SLICE) rank16[e0 + 1] = (ushort)atomicAdd(&bins[u1], 1u);
            if (u2 < SLICE) rank16[e0 + 2] = (ushort)atomicAdd(&bins[u2], 1u);
            if (u3 < SLICE) rank16[e0 + 3] = (ushort)atomicAdd(&bins[u3], 1u);
        }
    } else {
        for (int i = threadIdx.x; i < CHUNK_E / 4; i += 1024) {
            int4 v = ep4[i];
            unsigned u0 = (unsigned)(v.x - s0);
            unsigned u1 = (unsigned)(v.y - s0);
            unsigned u2 = (unsigned)(v.z - s0);
            unsigned u3 = (unsigned)(v.w - s0);
            if (u0 < SLICE) atomicAdd(&bins[u0], 1u);
            if (u1 < SLICE) atomicAdd(&bins[u1], 1u);
            if (u2 < SLICE) atomicAdd(&bins[u2], 1u);
            if (u3 < SLICE) atomicAdd(&bins[u3], 1u);
        }
    }
    __syncthreads();

    unsigned* pp = (isdst ? p_in : p_out) + (size_t)ci * N_NODES + s0;
    for (int i = threadIdx.x; i < SLICE; i += 1024) pp[i] = bins[i];
}

// ---------------------------------------------------------------------------
// Kernel 2: per-node reduction: deg_out = sum(p_out); exclusive prefix of
// p_in over chunks (in place) -> deg_in.
// ---------------------------------------------------------------------------
__global__ __launch_bounds__(256)
void prefix_kernel(const unsigned* __restrict__ p_out, unsigned* __restrict__ p_in,
                   unsigned* __restrict__ deg_out, unsigned* __restrict__ deg_in) {
    int n = blockIdx.x * 256 + threadIdx.x;
    if (n >= N_NODES) return;
    unsigned so = 0;
    #pragma unroll
    for (int c = 0; c < NCHUNK; ++c) so += p_out[(size_t)c * N_NODES + n];
    deg_out[n] = so;
    unsigned run = 0;
    #pragma unroll
    for (int c = 0; c < NCHUNK; ++c) {
        unsigned t = p_in[(size_t)c * N_NODES + n];
        p_in[(size_t)c * N_NODES + n] = run;
        run += t;
    }
    deg_in[n] = run;
}

// ---------------------------------------------------------------------------
// Kernel 3: W / skipW -> bf16 MFMA B-fragment-major; + params table
// params[col] = {b, gamma, beta, skip_b}  (float4, col = 0..255)
// ---------------------------------------------------------------------------
__global__ void wcvt_kernel(const float* __restrict__ W, const float* __restrict__ sW,
                            const float* __restrict__ bvec, const float* __restrict__ gamma,
                            const float* __restrict__ beta, const float* __restrict__ skipb,
                            ushort* __restrict__ Wfrag, ushort* __restrict__ sWfrag,
                            float4* __restrict__ params) {
    int tid = blockIdx.x * blockDim.x + threadIdx.x;
    if (tid >= 8448) return;
    if (tid >= 8192) {
        int i = tid - 8192;   // 0..255
        params[i] = make_float4(bvec[i], gamma[i], beta[i], skipb[i]);
        return;
    }
    const float* srcm = (tid < 4096) ? W : sW;
    ushort* dstm = (tid < 4096) ? Wfrag : sWfrag;
    int u = tid & 4095;
    int lane = u & 63;
    int ks = (u >> 6) & 3;
    int n = u >> 8;
    int c = lane & 15, g = lane >> 4;
    int col = n * 16 + c;
    int k0 = ks * 32 + g * 8;
    ushort4 lo, hi;
    lo.x = (ushort)f2bf(srcm[(size_t)(k0 + 0) * HID_DIM + col]);
    lo.y = (ushort)f2bf(srcm[(size_t)(k0 + 1) * HID_DIM + col]);
    lo.z = (ushort)f2bf(srcm[(size_t)(k0 + 2) * HID_DIM + col]);
    lo.w = (ushort)f2bf(srcm[(size_t)(k0 + 3) * HID_DIM + col]);
    hi.x = (ushort)f2bf(srcm[(size_t)(k0 + 4) * HID_DIM + col]);
    hi.y = (ushort)f2bf(srcm[(size_t)(k0 + 5) * HID_DIM + col]);
    hi.z = (ushort)f2bf(srcm[(size_t)(k0 + 6) * HID_DIM + col]);
    hi.w = (ushort)f2bf(srcm[(size_t)(k0 + 7) * HID_DIM + col]);
    *(ushort4*)(dstm + (size_t)u * 8)     = lo;
    *(ushort4*)(dstm + (size_t)u * 8 + 4) = hi;
}

// ---------------------------------------------------------------------------
// Kernel 4: single-block exclusive scan (4 elems/thread) deg_in -> row_ptr
// ---------------------------------------------------------------------------
__global__ __launch_bounds__(1024)
void scan_kernel(const unsigned* __restrict__ deg_in, unsigned* __restrict__ row_ptr) {
    __shared__ unsigned wsum[16];
    __shared__ unsigned carry_s;
    if (threadIdx.x == 0) carry_s = 0;
    __syncthreads();
    const int lane = threadIdx.x & 63;
    const int wid  = threadIdx.x >> 6;
    for (int base = 0; base < N_NODES; base += 4096) {
        int i0 = base + threadIdx.x * 4;
        unsigned d0 = 0, d1 = 0, d2 = 0, d3 = 0;
        if (i0 < N_NODES) {
            uint4 v = *(const uint4*)(deg_in + i0);
            d0 = v.x; d1 = v.y; d2 = v.z; d3 = v.w;
        }
        unsigned t = d0 + d1 + d2 + d3;
        unsigned x = t;
        #pragma unroll
        for (int d = 1; d < 64; d <<= 1) {
            unsigned tt = __shfl_up(x, d, 64);
            if (lane >= d) x += tt;
        }
        if (lane == 63) wsum[wid] = x;
        __syncthreads();
        if (threadIdx.x == 0) {
            unsigned run = carry_s;
            #pragma unroll
            for (int w = 0; w < 16; ++w) { unsigned tmp = wsum[w]; wsum[w] = run; run += tmp; }
            carry_s = run;
        }
        __syncthreads();
        if (i0 < N_NODES) {
            unsigned b = wsum[wid] + (x - t);
            uint4 rp;
            rp.x = b; rp.y = b + d0; rp.z = b + d0 + d1; rp.w = b + d0 + d1 + d2;
            *(uint4*)(row_ptr + i0) = rp;
        }
        __syncthreads();
    }
    if (threadIdx.x == 0) row_ptr[N_NODES] = carry_s;
}

// ---------------------------------------------------------------------------
// Kernel 5 (pre2), fused by block range:
//   [0, 6250)       : atomic-free CSR fill via chunk-prefix + within-chunk rank
//   [6250, 18750)   : featn = bf16(feat * norm_src)
// ---------------------------------------------------------------------------
__global__ __launch_bounds__(256)
void pre2_kernel(const int* __restrict__ src, const int* __restrict__ dst,
                 const unsigned* __restrict__ row_ptr, const unsigned* __restrict__ p_in,
                 const ushort* __restrict__ rank16, unsigned* __restrict__ edge_src,
                 const float* __restrict__ feat, const unsigned* __restrict__ deg_out,
                 ushort* __restrict__ featn) {
    const int b = blockIdx.x;
    if (b < EDGE_BLOCKS) {
        int e = b * 256 + threadIdx.x;
        int d = dst[e];
        int c = e / CHUNK_E;
        unsigned pos = row_ptr[d] + p_in[(size_t)c * N_NODES + d] + (unsigned)rank16[e];
        edge_src[pos] = (unsigned)src[e];
    } else {
        int id = (b - EDGE_BLOCKS) * 256 + threadIdx.x;   // exact N_NODES*32
        int row = id >> 5;
        float ns = rsqrtf(fmaxf((float)deg_out[row], 1.f));
        float4 v = ((const float4*)feat)[id];
        ushort4 o;
        o.x = (ushort)f2bf(v.x * ns);
        o.y = (ushort)f2bf(v.y * ns);
        o.z = (ushort)f2bf(v.z * ns);
        o.w = (ushort)f2bf(v.w * ns);
        ((ushort4*)featn)[id] = o;
    }
}

// ---------------------------------------------------------------------------
// Kernel 6: row-per-wave gather SpMM over bf16 featn -> aggb (bf16)
// ---------------------------------------------------------------------------
__global__ __launch_bounds__(256)
void spmm_kernel(const ushort* __restrict__ featn,
                 const unsigned* __restrict__ row_ptr, const unsigned* __restrict__ edge_src,
                 unsigned* __restrict__ aggb_u32) {
    int gw = (blockIdx.x * 256 + threadIdx.x) >> 6;
    int lane = threadIdx.x & 63;
    if (gw >= N_NODES) return;
    unsigned beg = row_ptr[gw], end = row_ptr[gw + 1];
    float a0 = 0.f, a1 = 0.f;
    unsigned e = beg;
    for (; e + 4 <= end; e += 4) {
        unsigned s0 = edge_src[e + 0];
        unsigned s1 = edge_src[e + 1];
        unsigned s2 = edge_src[e + 2];
        unsigned s3 = edge_src[e + 3];
        unsigned v0 = *(const unsigned*)(featn + (size_t)s0 * IN_DIM + 2 * lane);
        unsigned v1 = *(const unsigned*)(featn + (size_t)s1 * IN_DIM + 2 * lane);
        unsigned v2 = *(const unsigned*)(featn + (size_t)s2 * IN_DIM + 2 * lane);
        unsigned v3 = *(const unsigned*)(featn + (size_t)s3 * IN_DIM + 2 * lane);
        a0 += __builtin_bit_cast(float, v0 << 16);
        a1 += __builtin_bit_cast(float, v0 & 0xffff0000u);
        a0 += __builtin_bit_cast(float, v1 << 16);
        a1 += __builtin_bit_cast(float, v1 & 0xffff0000u);
        a0 += __builtin_bit_cast(float, v2 << 16);
        a1 += __builtin_bit_cast(float, v2 & 0xffff0000u);
        a0 += __builtin_bit_cast(float, v3 << 16);
        a1 += __builtin_bit_cast(float, v3 & 0xffff0000u);
    }
    for (; e < end; ++e) {
        unsigned s = edge_src[e];
        unsigned v = *(const unsigned*)(featn + (size_t)s * IN_DIM + 2 * lane);
        a0 += __builtin_bit_cast(float, v << 16);
        a1 += __builtin_bit_cast(float, v & 0xffff0000u);
    }
    float nd = rsqrtf(fmaxf((float)(end - beg), 1.0f));
    unsigned lo = (unsigned)(ushort)f2bf(a0 * nd);
    unsigned hi = (unsigned)(ushort)f2bf(a1 * nd);
    aggb_u32[(size_t)gw * (IN_DIM / 2) + lane] = lo | (hi << 16);
}

// ---------------------------------------------------------------------------
// Kernel 7: FUSED GEMM1 + LN + ReLU + GEMM2 + biases -> out, v2.
// Register-disciplined: per-col constants live in LDS (4 KB params), not
// VGPRs; A1 dies after GEMM1; F converted to A2 before LN-apply.
// 256 blocks (1/CU) x 1024 threads (16 waves), launch_bounds(1024,4):
// 4 waves/SIMD @ <=128 VGPR. LDS = 128 KB weights + 4 KB params.
// ---------------------------------------------------------------------------
__global__ __launch_bounds__(1024, 4)
void gemm_fused_kernel(const ushort* __restrict__ aggb, const float* __restrict__ feat,
                       const ushort* __restrict__ Wfrag, const ushort* __restrict__ sWfrag,
                       const float4* __restrict__ params, float* __restrict__ out) {
    __shared__ __align__(16) ushort Blds[65536];   // 128 KB: [0]=W, [32768]=sW
    __shared__ float4 Plds[256];                   // 4 KB {b, gamma, beta, skipb}
    const int tid = threadIdx.x;
    #pragma unroll
    for (int i = 0; i < 4; ++i)
        ((uint4*)Blds)[tid + i * 1024] = ((const uint4*)Wfrag)[tid + i * 1024];
    #pragma unroll
    for (int i = 0; i < 4; ++i)
        ((uint4*)Blds)[4096 + tid + i * 1024] = ((const uint4*)sWfrag)[tid + i * 1024];
    if (tid < 256) Plds[tid] = params[tid];
    __syncthreads();

    const int lane = tid & 63;
    const int c = lane & 15, g = lane >> 4;
    const int gw = blockIdx.x * 16 + (tid >> 6);

    for (int t = gw; t < NT; t += GEMM_WAVES) {
        const int r0 = t * 16;

        // ---- GEMM 1: aggb @ W + b (A1 scoped: dies after this block) -------
        f32x4 acc[16];
        {
            bf16x8 A1[4];
            #pragma unroll
            for (int ks = 0; ks < 4; ++ks)
                A1[ks] = *(const bf16x8*)(aggb + (size_t)(r0 + c) * IN_DIM + ks * 32 + g * 8);
            #pragma unroll
            for (int n = 0; n < 16; ++n) {
                float bb = Plds[n * 16 + c].x;
                acc[n] = (f32x4){bb, bb, bb, bb};
                #pragma unroll
                for (int ks = 0; ks < 4; ++ks) {
                    bf16x8 b = *(const bf16x8*)(Blds + ((n * 4 + ks) * 64 + lane) * 8);
                    acc[n] = __builtin_amdgcn_mfma_f32_16x16x32_bf16(A1[ks], b, acc[n], 0, 0, 0);
                }
            }
        }

        // ---- issue feat loads now; LN stats hide their latency -------------
        f32x4 F[8];
        #pragma unroll
        for (int ks = 0; ks < 4; ++ks) {
            const float* fp = feat + (size_t)(r0 + c) * IN_DIM + ks * 32 + g * 8;
            F[2 * ks]     = *(const f32x4*)fp;
            F[2 * ks + 1] = *(const f32x4*)(fp + 4);
        }

        // ---- LN stats (in-wave, cols = 16 lanes x 16 regs) ------------------
        float mu[4], rstd[4];
        {
            float s1[4], s2[4];
            #pragma unroll
            for (int j = 0; j < 4; ++j) { s1[j] = 0.f; s2[j] = 0.f; }
            #pragma unroll
            for (int n = 0; n < 16; ++n) {
                #pragma unroll
                for (int j = 0; j < 4; ++j) {
                    s1[j] += acc[n][j];
                    s2[j] = fmaf(acc[n][j], acc[n][j], s2[j]);
                }
            }
            #pragma unroll
            for (int m = 1; m <= 8; m <<= 1) {
                #pragma unroll
                for (int j = 0; j < 4; ++j) {
                    s1[j] += __shfl_xor(s1[j], m, 64);
                    s2[j] += __shfl_xor(s2[j], m, 64);
                }
            }
            #pragma unroll
            for (int j = 0; j < 4; ++j) {
                mu[j] = s1[j] * (1.f / HID_DIM);
                float var = s2[j] * (1.f / HID_DIM) - mu[j] * mu[j];
                rstd[j] = rsqrtf(var + LN_EPS);
            }
        }

        // ---- convert F -> A2 (frees 32 VGPRs before LN-apply) ---------------
        bf16x8 A2[4];
        #pragma unroll
        for (int ks = 0; ks < 4; ++ks) {
            f32x4 u = F[2 * ks], v = F[2 * ks + 1];
            bf16x8 a;
            a[0] = f2bf(u[0]); a[1] = f2bf(u[1]); a[2] = f2bf(u[2]); a[3] = f2bf(u[3]);
            a[4] = f2bf(v[0]); a[5] = f2bf(v[1]); a[6] = f2bf(v[2]); a[7] = f2bf(v[3]);
            A2[ks] = a;
        }

        // ---- LN apply + ReLU + skip_b (params from LDS) ---------------------
        #pragma unroll
        for (int n = 0; n < 16; ++n) {
            float4 p = Plds[n * 16 + c];   // {b, gamma, beta, skipb}
            #pragma unroll
            for (int j = 0; j < 4; ++j)
                acc[n][j] = fmaxf(fmaf((acc[n][j] - mu[j]) * rstd[j], p.y, p.z), 0.f) + p.w;
        }

        // ---- GEMM 2: + feat @ skipW ------------------------------------------
        #pragma unroll
        for (int n = 0; n < 16; ++n) {
            #pragma unroll
            for (int ks = 0; ks < 4; ++ks) {
                bf16x8 b = *(const bf16x8*)(Blds + 32768 + ((n * 4 + ks) * 64 + lane) * 8);
                acc[n] = __builtin_amdgcn_mfma_f32_16x16x32_bf16(A2[ks], b, acc[n], 0, 0, 0);
            }
        }

        // ---- store out (f32 row-major) ----------------------------------------
        #pragma unroll
        for (int n = 0; n < 16; ++n) {
            #pragma unroll
            for (int j = 0; j < 4; ++j)
                out[(size_t)(r0 + g * 4 + j) * HID_DIM + n * 16 + c] = acc[n][j];
        }
    }
}

// ---------------------------------------------------------------------------
extern "C" void kernel_launch(void* const* d_in, const int* in_sizes, int n_in,
                              void* d_out, int out_size, void* d_ws, size_t ws_size,
                              hipStream_t stream) {
    const float* feat  = (const float*)d_in[0];
    const int*   src   = (const int*)d_in[1];
    const int*   dst   = (const int*)d_in[2];
    const float* W     = (const float*)d_in[3];
    const float* bvec  = (const float*)d_in[4];
    const float* gamma = (const float*)d_in[5];
    const float* beta  = (const float*)d_in[6];
    const float* skipW = (const float*)d_in[7];
    const float* skipb = (const float*)d_in[8];
    float* out = (float*)d_out;

    // workspace, peak ≈ 77 MB:
    // [Wfrag 64K][sWfrag 64K][params 4K][aggb 25.6M][featn 25.6M (p_out 12.8M
    //  aliases it; dead before fcvt writes featn) | edge_src 6.4M |
    //  rank16 3.2M | p_in 12.8M | deg_out .4 | deg_in .4 | row_ptr .4]
    char* ws = (char*)d_ws;
    ushort*   Wfrag    = (ushort*)ws;                               // 64 KB
    ushort*   sWfrag   = Wfrag + 32768;                             // 64 KB
    float4*   params   = (float4*)(sWfrag + 32768);                 // 4 KB
    ushort*   aggb     = (ushort*)(params + 256);                   // 25.6 MB
    char*     xbase    = (char*)(aggb + (size_t)N_NODES * IN_DIM);
    ushort*   featn    = (ushort*)xbase;                            // 25.6 MB
    unsigned* p_out    = (unsigned*)xbase;                          // 12.8 MB (alias featn)
    unsigned* edge_src = (unsigned*)(featn + (size_t)N_NODES * IN_DIM); // 6.4 MB
    ushort*   rank16   = (ushort*)(edge_src + N_EDGES);             // 3.2 MB
    unsigned* p_in     = (unsigned*)(rank16 + N_EDGES);             // 12.8 MB
    unsigned* deg_out  = p_in + (size_t)NCHUNK * N_NODES;           // 400 KB
    unsigned* deg_in   = deg_out + N_NODES;                         // 400 KB
    unsigned* row_ptr  = deg_in + N_NODES;                          // 400 KB + pad

    wcvt_kernel<<<33, 256, 0, stream>>>(W, skipW, bvec, gamma, beta, skipb,
                                        Wfrag, sWfrag, params);

    hist_kernel<<<2 * HBLK, 1024, 0, stream>>>(src, dst, p_out, p_in, rank16);

    prefix_kernel<<<(N_NODES + 255) / 256, 256, 0, stream>>>(p_out, p_in, deg_out, deg_in);

    scan_kernel<<<1, 1024, 0, stream>>>(deg_in, row_ptr);

    pre2_kernel<<<EDGE_BLOCKS + FCVT_BLOCKS, 256, 0, stream>>>(
        src, dst, row_ptr, p_in, rank16, edge_src, feat, deg_out, featn);

    spmm_kernel<<<(N_NODES * 64 + 255) / 256, 256, 0, stream>>>(featn, row_ptr, edge_src,
                                                                (unsigned*)aggb);

    gemm_fused_kernel<<<GEMM_BLOCKS, 1024, 0, stream>>>(
        aggb, feat, Wfrag, sWfrag, params, out);
}

// Round 12
// 540.011 us; speedup vs baseline: 1.2480x; 1.2480x over previous
//
#include <hip/hip_runtime.h>
#include <hip/hip_bf16.h>

#define N_NODES 100000
#define N_EDGES 1600000
#define IN_DIM 128
#define HID_DIM 256
#define LN_EPS 1e-5f
#define NT (N_NODES / 16)   // 6250 16-row tiles, exact

// histogram geometry
#define NCHUNK 32
#define CHUNK_E (N_EDGES / NCHUNK)     // 50000 edges/chunk (12500 int4, exact)
#define NSLICE 8
#define SLICE (N_NODES / NSLICE)       // 12500 nodes/slice (50 KB LDS bins)
#define HBLK (NCHUNK * NSLICE)         // 256 blocks per histogrammed array

#define EDGE_BLOCKS (N_EDGES / 256)       // 6250, exact
#define FCVT_BLOCKS (N_NODES * 32 / 256)  // 12500, exact

// fused gemm geometry: 256 persistent blocks (1/CU), 8 waves each
#define GEMM_BLOCKS 256
#define GEMM_WAVES (GEMM_BLOCKS * 8)   // 2048 global waves

typedef short bf16x8 __attribute__((ext_vector_type(8)));
typedef float f32x4  __attribute__((ext_vector_type(4)));

static __device__ __forceinline__ short f2bf(float x) {
    return __builtin_bit_cast(short, __float2bfloat16(x));  // RNE round
}
static __device__ __forceinline__ float bf2f_lo(unsigned v) {
    return __builtin_bit_cast(float, v << 16);
}
static __device__ __forceinline__ float bf2f_hi(unsigned v) {
    return __builtin_bit_cast(float, v & 0xffff0000u);
}

// ---------------------------------------------------------------------------
// Kernel 1: LDS-bin histograms — NO global atomics.
//   blocks [0, 256)   : histogram of src  -> p_out[chunk][node]
//   blocks [256, 512) : histogram of dst  -> p_in[chunk][node], and the LDS
//                       atomic's return value = within-chunk rank -> rank16[e]
// ---------------------------------------------------------------------------
__global__ __launch_bounds__(1024)
void hist_kernel(const int* __restrict__ src, const int* __restrict__ dst,
                 unsigned* __restrict__ p_out, unsigned* __restrict__ p_in,
                 ushort* __restrict__ rank16) {
    __shared__ unsigned bins[SLICE];   // 50 KB
    const int b = blockIdx.x;
    const bool isdst = (b >= HBLK);
    const int bb = isdst ? (b - HBLK) : b;
    const int ci = bb >> 3;            // chunk 0..31
    const int si = bb & 7;             // slice 0..7
    const int s0 = si * SLICE;

    for (int i = threadIdx.x; i < SLICE; i += 1024) bins[i] = 0;
    __syncthreads();

    const int4* ep4 = (const int4*)((isdst ? dst : src) + ci * CHUNK_E);
    if (isdst) {
        const int ebase = ci * CHUNK_E;
        for (int i = threadIdx.x; i < CHUNK_E / 4; i += 1024) {
            int4 v = ep4[i];
            int e0 = ebase + i * 4;
            unsigned u0 = (unsigned)(v.x - s0);
            unsigned u1 = (unsigned)(v.y - s0);
            unsigned u2 = (unsigned)(v.z - s0);
            unsigned u3 = (unsigned)(v.w - s0);
            if (u0 < SLICE) rank16[e0 + 0] = (ushort)atomicAdd(&bins[u0], 1u);
            if (u1 < SLICE) rank16[e0 + 1] = (ushort)atomicAdd(&bins[u1], 1u);
            if (u2 < SLICE) rank16[e0 + 2] = (ushort)atomicAdd(&bins[u2], 1u);
            if (u3 < SLICE) rank16[e0 + 3] = (ushort)atomicAdd(&bins[u3], 1u);
        }
    } else {
        for (int i = threadIdx.x; i < CHUNK_E / 4; i += 1024) {
            int4 v = ep4[i];
            unsigned u0 = (unsigned)(v.x - s0);
            unsigned u1 = (unsigned)(v.y - s0);
            unsigned u2 = (unsigned)(v.z - s0);
            unsigned u3 = (unsigned)(v.w - s0);
            if (u0 < SLICE) atomicAdd(&bins[u0], 1u);
            if (u1 < SLICE) atomicAdd(&bins[u1], 1u);
            if (u2 < SLICE) atomicAdd(&bins[u2], 1u);
            if (u3 < SLICE) atomicAdd(&bins[u3], 1u);
        }
    }
    __syncthreads();

    unsigned* pp = (isdst ? p_in : p_out) + (size_t)ci * N_NODES + s0;
    for (int i = threadIdx.x; i < SLICE; i += 1024) pp[i] = bins[i];
}

// ---------------------------------------------------------------------------
// Kernel 2: per-node: nsrc = rsqrt(max(deg_out,1)) from p_out partials;
// exclusive prefix of p_in over chunks (in place) -> deg_in.
// ---------------------------------------------------------------------------
__global__ __launch_bounds__(256)
void prefix_kernel(const unsigned* __restrict__ p_out, unsigned* __restrict__ p_in,
                   float* __restrict__ nsrc, unsigned* __restrict__ deg_in) {
    int n = blockIdx.x * 256 + threadIdx.x;
    if (n >= N_NODES) return;
    unsigned so = 0;
    #pragma unroll
    for (int c = 0; c < NCHUNK; ++c) so += p_out[(size_t)c * N_NODES + n];
    nsrc[n] = rsqrtf(fmaxf((float)so, 1.f));
    unsigned run = 0;
    #pragma unroll
    for (int c = 0; c < NCHUNK; ++c) {
        unsigned t = p_in[(size_t)c * N_NODES + n];
        p_in[(size_t)c * N_NODES + n] = run;
        run += t;
    }
    deg_in[n] = run;
}

// ---------------------------------------------------------------------------
// Kernel 3: W / skipW -> bf16 MFMA B-fragment-major; + params table
// params[col] = {b, gamma, beta, skip_b}
// ---------------------------------------------------------------------------
__global__ void wcvt_kernel(const float* __restrict__ W, const float* __restrict__ sW,
                            const float* __restrict__ bvec, const float* __restrict__ gamma,
                            const float* __restrict__ beta, const float* __restrict__ skipb,
                            ushort* __restrict__ Wfrag, ushort* __restrict__ sWfrag,
                            float4* __restrict__ params) {
    int tid = blockIdx.x * blockDim.x + threadIdx.x;
    if (tid >= 8448) return;
    if (tid >= 8192) {
        int i = tid - 8192;   // 0..255
        params[i] = make_float4(bvec[i], gamma[i], beta[i], skipb[i]);
        return;
    }
    const float* srcm = (tid < 4096) ? W : sW;
    ushort* dstm = (tid < 4096) ? Wfrag : sWfrag;
    int u = tid & 4095;
    int lane = u & 63;
    int ks = (u >> 6) & 3;
    int n = u >> 8;
    int c = lane & 15, g = lane >> 4;
    int col = n * 16 + c;
    int k0 = ks * 32 + g * 8;
    ushort4 lo, hi;
    lo.x = (ushort)f2bf(srcm[(size_t)(k0 + 0) * HID_DIM + col]);
    lo.y = (ushort)f2bf(srcm[(size_t)(k0 + 1) * HID_DIM + col]);
    lo.z = (ushort)f2bf(srcm[(size_t)(k0 + 2) * HID_DIM + col]);
    lo.w = (ushort)f2bf(srcm[(size_t)(k0 + 3) * HID_DIM + col]);
    hi.x = (ushort)f2bf(srcm[(size_t)(k0 + 4) * HID_DIM + col]);
    hi.y = (ushort)f2bf(srcm[(size_t)(k0 + 5) * HID_DIM + col]);
    hi.z = (ushort)f2bf(srcm[(size_t)(k0 + 6) * HID_DIM + col]);
    hi.w = (ushort)f2bf(srcm[(size_t)(k0 + 7) * HID_DIM + col]);
    *(ushort4*)(dstm + (size_t)u * 8)     = lo;
    *(ushort4*)(dstm + (size_t)u * 8 + 4) = hi;
}

// ---------------------------------------------------------------------------
// Kernel 4: single-block exclusive scan (4 elems/thread) deg_in -> row_ptr
// ---------------------------------------------------------------------------
__global__ __launch_bounds__(1024)
void scan_kernel(const unsigned* __restrict__ deg_in, unsigned* __restrict__ row_ptr) {
    __shared__ unsigned wsum[16];
    __shared__ unsigned carry_s;
    if (threadIdx.x == 0) carry_s = 0;
    __syncthreads();
    const int lane = threadIdx.x & 63;
    const int wid  = threadIdx.x >> 6;
    for (int base = 0; base < N_NODES; base += 4096) {
        int i0 = base + threadIdx.x * 4;
        unsigned d0 = 0, d1 = 0, d2 = 0, d3 = 0;
        if (i0 < N_NODES) {
            uint4 v = *(const uint4*)(deg_in + i0);
            d0 = v.x; d1 = v.y; d2 = v.z; d3 = v.w;
        }
        unsigned t = d0 + d1 + d2 + d3;
        unsigned x = t;
        #pragma unroll
        for (int d = 1; d < 64; d <<= 1) {
            unsigned tt = __shfl_up(x, d, 64);
            if (lane >= d) x += tt;
        }
        if (lane == 63) wsum[wid] = x;
        __syncthreads();
        if (threadIdx.x == 0) {
            unsigned run = carry_s;
            #pragma unroll
            for (int w = 0; w < 16; ++w) { unsigned tmp = wsum[w]; wsum[w] = run; run += tmp; }
            carry_s = run;
        }
        __syncthreads();
        if (i0 < N_NODES) {
            unsigned b = wsum[wid] + (x - t);
            uint4 rp;
            rp.x = b; rp.y = b + d0; rp.z = b + d0 + d1; rp.w = b + d0 + d1 + d2;
            *(uint4*)(row_ptr + i0) = rp;
        }
        __syncthreads();
    }
    if (threadIdx.x == 0) row_ptr[N_NODES] = carry_s;
}

// ---------------------------------------------------------------------------
// Kernel 5 (pre2), fused by block range:
//   [0, 6250)       : atomic-free CSR fill via chunk-prefix + within-chunk rank
//   [6250, 18750)   : featb = bf16(feat)   (UNscaled; spmm applies nsrc)
// ---------------------------------------------------------------------------
__global__ __launch_bounds__(256)
void pre2_kernel(const int* __restrict__ src, const int* __restrict__ dst,
                 const unsigned* __restrict__ row_ptr, const unsigned* __restrict__ p_in,
                 const ushort* __restrict__ rank16, unsigned* __restrict__ edge_src,
                 const float* __restrict__ feat, ushort* __restrict__ featb) {
    const int b = blockIdx.x;
    if (b < EDGE_BLOCKS) {
        int e = b * 256 + threadIdx.x;
        int d = dst[e];
        int c = e / CHUNK_E;
        unsigned pos = row_ptr[d] + p_in[(size_t)c * N_NODES + d] + (unsigned)rank16[e];
        edge_src[pos] = (unsigned)src[e];
    } else {
        int id = (b - EDGE_BLOCKS) * 256 + threadIdx.x;   // exact N_NODES*32
        float4 v = ((const float4*)feat)[id];
        ushort4 o;
        o.x = (ushort)f2bf(v.x);
        o.y = (ushort)f2bf(v.y);
        o.z = (ushort)f2bf(v.z);
        o.w = (ushort)f2bf(v.w);
        ((ushort4*)featb)[id] = o;
    }
}

// ---------------------------------------------------------------------------
// Kernel 6: row-per-wave gather SpMM over bf16 featb, scale by nsrc[s] (f32
// broadcast load) -> aggb (bf16), norm_dst applied at the end.
// ---------------------------------------------------------------------------
__global__ __launch_bounds__(256)
void spmm_kernel(const ushort* __restrict__ featb, const float* __restrict__ nsrc,
                 const unsigned* __restrict__ row_ptr, const unsigned* __restrict__ edge_src,
                 unsigned* __restrict__ aggb_u32) {
    int gw = (blockIdx.x * 256 + threadIdx.x) >> 6;
    int lane = threadIdx.x & 63;
    if (gw >= N_NODES) return;
    unsigned beg = row_ptr[gw], end = row_ptr[gw + 1];
    float a0 = 0.f, a1 = 0.f;
    unsigned e = beg;
    for (; e + 4 <= end; e += 4) {
        unsigned s0 = edge_src[e + 0];
        unsigned s1 = edge_src[e + 1];
        unsigned s2 = edge_src[e + 2];
        unsigned s3 = edge_src[e + 3];
        float n0 = nsrc[s0], n1 = nsrc[s1], n2 = nsrc[s2], n3 = nsrc[s3];
        unsigned v0 = *(const unsigned*)(featb + (size_t)s0 * IN_DIM + 2 * lane);
        unsigned v1 = *(const unsigned*)(featb + (size_t)s1 * IN_DIM + 2 * lane);
        unsigned v2 = *(const unsigned*)(featb + (size_t)s2 * IN_DIM + 2 * lane);
        unsigned v3 = *(const unsigned*)(featb + (size_t)s3 * IN_DIM + 2 * lane);
        a0 = fmaf(bf2f_lo(v0), n0, a0); a1 = fmaf(bf2f_hi(v0), n0, a1);
        a0 = fmaf(bf2f_lo(v1), n1, a0); a1 = fmaf(bf2f_hi(v1), n1, a1);
        a0 = fmaf(bf2f_lo(v2), n2, a0); a1 = fmaf(bf2f_hi(v2), n2, a1);
        a0 = fmaf(bf2f_lo(v3), n3, a0); a1 = fmaf(bf2f_hi(v3), n3, a1);
    }
    for (; e < end; ++e) {
        unsigned s = edge_src[e];
        float ns = nsrc[s];
        unsigned v = *(const unsigned*)(featb + (size_t)s * IN_DIM + 2 * lane);
        a0 = fmaf(bf2f_lo(v), ns, a0); a1 = fmaf(bf2f_hi(v), ns, a1);
    }
    float nd = rsqrtf(fmaxf((float)(end - beg), 1.0f));
    unsigned lo = (unsigned)(ushort)f2bf(a0 * nd);
    unsigned hi = (unsigned)(ushort)f2bf(a1 * nd);
    aggb_u32[(size_t)gw * (IN_DIM / 2) + lane] = lo | (hi << 16);
}

// ---------------------------------------------------------------------------
// Kernel 7: FUSED GEMM1 + LN + ReLU + GEMM2 + biases -> out, v3.
// NO-SPILL design: live set ~110 regs (acc 64 + A 16 + stats + addr);
// amdgpu_waves_per_eu(2,2) pins 2 waves/EU -> 256-reg budget, allocator has
// no occupancy incentive to spill. A2 is a direct bf16 load from featb
// (no f32 staging, no cvt). Params in LDS. 8 waves, 132 KB LDS, 1 block/CU.
// ---------------------------------------------------------------------------
__attribute__((amdgpu_waves_per_eu(2, 2)))
__global__ __launch_bounds__(512)
void gemm_fused_kernel(const ushort* __restrict__ aggb, const ushort* __restrict__ featb,
                       const ushort* __restrict__ Wfrag, const ushort* __restrict__ sWfrag,
                       const float4* __restrict__ params, float* __restrict__ out) {
    __shared__ __align__(16) ushort Blds[65536];   // 128 KB: [0]=W, [32768]=sW
    __shared__ float4 Plds[256];                   // 4 KB {b, gamma, beta, skipb}
    const int tid = threadIdx.x;
    #pragma unroll
    for (int i = 0; i < 8; ++i)
        ((uint4*)Blds)[tid + i * 512] = ((const uint4*)Wfrag)[tid + i * 512];
    #pragma unroll
    for (int i = 0; i < 8; ++i)
        ((uint4*)Blds)[4096 + tid + i * 512] = ((const uint4*)sWfrag)[tid + i * 512];
    if (tid < 256) Plds[tid] = params[tid];
    __syncthreads();

    const int lane = tid & 63;
    const int c = lane & 15, g = lane >> 4;
    const int gw = blockIdx.x * 8 + (tid >> 6);

    for (int t = gw; t < NT; t += GEMM_WAVES) {
        const int r0 = t * 16;

        // ---- GEMM 1: aggb @ W + b (A1 scoped) -------------------------------
        f32x4 acc[16];
        {
            bf16x8 A1[4];
            #pragma unroll
            for (int ks = 0; ks < 4; ++ks)
                A1[ks] = *(const bf16x8*)(aggb + (size_t)(r0 + c) * IN_DIM + ks * 32 + g * 8);
            #pragma unroll
            for (int n = 0; n < 16; ++n) {
                float bb = Plds[n * 16 + c].x;
                acc[n] = (f32x4){bb, bb, bb, bb};
                #pragma unroll
                for (int ks = 0; ks < 4; ++ks) {
                    bf16x8 b = *(const bf16x8*)(Blds + ((n * 4 + ks) * 64 + lane) * 8);
                    acc[n] = __builtin_amdgcn_mfma_f32_16x16x32_bf16(A1[ks], b, acc[n], 0, 0, 0);
                }
            }
        }

        // ---- A2: direct bf16 load (issued early; LN hides latency) ---------
        bf16x8 A2[4];
        #pragma unroll
        for (int ks = 0; ks < 4; ++ks)
            A2[ks] = *(const bf16x8*)(featb + (size_t)(r0 + c) * IN_DIM + ks * 32 + g * 8);

        // ---- LN stats (in-wave) ---------------------------------------------
        float mu[4], rstd[4];
        {
            float s1[4], s2[4];
            #pragma unroll
            for (int j = 0; j < 4; ++j) { s1[j] = 0.f; s2[j] = 0.f; }
            #pragma unroll
            for (int n = 0; n < 16; ++n) {
                #pragma unroll
                for (int j = 0; j < 4; ++j) {
                    s1[j] += acc[n][j];
                    s2[j] = fmaf(acc[n][j], acc[n][j], s2[j]);
                }
            }
            #pragma unroll
            for (int m = 1; m <= 8; m <<= 1) {
                #pragma unroll
                for (int j = 0; j < 4; ++j) {
                    s1[j] += __shfl_xor(s1[j], m, 64);
                    s2[j] += __shfl_xor(s2[j], m, 64);
                }
            }
            #pragma unroll
            for (int j = 0; j < 4; ++j) {
                mu[j] = s1[j] * (1.f / HID_DIM);
                float var = s2[j] * (1.f / HID_DIM) - mu[j] * mu[j];
                rstd[j] = rsqrtf(var + LN_EPS);
            }
        }

        // ---- LN apply + ReLU + skip_b (params from LDS) ---------------------
        #pragma unroll
        for (int n = 0; n < 16; ++n) {
            float4 p = Plds[n * 16 + c];   // {b, gamma, beta, skipb}
            #pragma unroll
            for (int j = 0; j < 4; ++j)
                acc[n][j] = fmaxf(fmaf((acc[n][j] - mu[j]) * rstd[j], p.y, p.z), 0.f) + p.w;
        }

        // ---- GEMM 2: + feat @ skipW ------------------------------------------
        #pragma unroll
        for (int n = 0; n < 16; ++n) {
            #pragma unroll
            for (int ks = 0; ks < 4; ++ks) {
                bf16x8 b = *(const bf16x8*)(Blds + 32768 + ((n * 4 + ks) * 64 + lane) * 8);
                acc[n] = __builtin_amdgcn_mfma_f32_16x16x32_bf16(A2[ks], b, acc[n], 0, 0, 0);
            }
        }

        // ---- store out (f32 row-major) ----------------------------------------
        #pragma unroll
        for (int n = 0; n < 16; ++n) {
            #pragma unroll
            for (int j = 0; j < 4; ++j)
                out[(size_t)(r0 + g * 4 + j) * HID_DIM + n * 16 + c] = acc[n][j];
        }
    }
}

// ---------------------------------------------------------------------------
extern "C" void kernel_launch(void* const* d_in, const int* in_sizes, int n_in,
                              void* d_out, int out_size, void* d_ws, size_t ws_size,
                              hipStream_t stream) {
    const float* feat  = (const float*)d_in[0];
    const int*   src   = (const int*)d_in[1];
    const int*   dst   = (const int*)d_in[2];
    const float* W     = (const float*)d_in[3];
    const float* bvec  = (const float*)d_in[4];
    const float* gamma = (const float*)d_in[5];
    const float* beta  = (const float*)d_in[6];
    const float* skipW = (const float*)d_in[7];
    const float* skipb = (const float*)d_in[8];
    float* out = (float*)d_out;

    // workspace, peak ≈ 77 MB:
    // [Wfrag 64K][sWfrag 64K][params 4K][aggb 25.6M][featb 25.6M (p_out 12.8M
    //  aliases it; dead before pre2 writes featb) | edge_src 6.4M |
    //  rank16 3.2M | p_in 12.8M | nsrc .4 | deg_in .4 | row_ptr .4]
    char* ws = (char*)d_ws;
    ushort*   Wfrag    = (ushort*)ws;                               // 64 KB
    ushort*   sWfrag   = Wfrag + 32768;                             // 64 KB
    float4*   params   = (float4*)(sWfrag + 32768);                 // 4 KB
    ushort*   aggb     = (ushort*)(params + 256);                   // 25.6 MB
    char*     xbase    = (char*)(aggb + (size_t)N_NODES * IN_DIM);
    ushort*   featb    = (ushort*)xbase;                            // 25.6 MB
    unsigned* p_out    = (unsigned*)xbase;                          // 12.8 MB (alias featb)
    unsigned* edge_src = (unsigned*)(featb + (size_t)N_NODES * IN_DIM); // 6.4 MB
    ushort*   rank16   = (ushort*)(edge_src + N_EDGES);             // 3.2 MB
    unsigned* p_in     = (unsigned*)(rank16 + N_EDGES);             // 12.8 MB
    float*    nsrc     = (float*)(p_in + (size_t)NCHUNK * N_NODES); // 400 KB
    unsigned* deg_in   = (unsigned*)(nsrc + N_NODES);               // 400 KB
    unsigned* row_ptr  = deg_in + N_NODES;                          // 400 KB + pad

    wcvt_kernel<<<33, 256, 0, stream>>>(W, skipW, bvec, gamma, beta, skipb,
                                        Wfrag, sWfrag, params);

    hist_kernel<<<2 * HBLK, 1024, 0, stream>>>(src, dst, p_out, p_in, rank16);

    prefix_kernel<<<(N_NODES + 255) / 256, 256, 0, stream>>>(p_out, p_in, nsrc, deg_in);

    scan_kernel<<<1, 1024, 0, stream>>>(deg_in, row_ptr);

    pre2_kernel<<<EDGE_BLOCKS + FCVT_BLOCKS, 256, 0, stream>>>(
        src, dst, row_ptr, p_in, rank16, edge_src, feat, featb);

    spmm_kernel<<<(N_NODES * 64 + 255) / 256, 256, 0, stream>>>(featb, nsrc, row_ptr,
                                                                edge_src, (unsigned*)aggb);

    gemm_fused_kernel<<<GEMM_BLOCKS, 512, 0, stream>>>(
        aggb, featb, Wfrag, sWfrag, params, out);
}

// Round 13
// 292.162 us; speedup vs baseline: 2.3067x; 1.8483x over previous
//
#include <hip/hip_runtime.h>
#include <hip/hip_bf16.h>

#define N_NODES 100000
#define N_EDGES 1600000
#define IN_DIM 128
#define HID_DIM 256
#define LN_EPS 1e-5f
#define NT (N_NODES / 16)   // 6250 16-row tiles, exact

// histogram geometry
#define NCHUNK 32
#define CHUNK_E (N_EDGES / NCHUNK)     // 50000 edges/chunk (12500 int4, exact)
#define NSLICE 8
#define SLICE (N_NODES / NSLICE)       // 12500 nodes/slice (50 KB LDS bins)
#define HBLK (NCHUNK * NSLICE)         // 256 blocks per histogrammed array

#define EDGE_BLOCKS (N_EDGES / 256)       // 6250, exact
#define FCVT_BLOCKS (N_NODES * 32 / 256)  // 12500, exact

typedef short bf16x8 __attribute__((ext_vector_type(8)));
typedef float f32x4  __attribute__((ext_vector_type(4)));

static __device__ __forceinline__ short f2bf(float x) {
    return __builtin_bit_cast(short, __float2bfloat16(x));  // RNE round
}
static __device__ __forceinline__ float bf2f_lo(unsigned v) {
    return __builtin_bit_cast(float, v << 16);
}
static __device__ __forceinline__ float bf2f_hi(unsigned v) {
    return __builtin_bit_cast(float, v & 0xffff0000u);
}

// ---------------------------------------------------------------------------
// Kernel 1: LDS-bin histograms — NO global atomics.
//   blocks [0, 256)   : histogram of src  -> p_out[chunk][node]
//   blocks [256, 512) : histogram of dst  -> p_in[chunk][node], and the LDS
//                       atomic's return value = within-chunk rank -> rank16[e]
// ---------------------------------------------------------------------------
__global__ __launch_bounds__(1024)
void hist_kernel(const int* __restrict__ src, const int* __restrict__ dst,
                 unsigned* __restrict__ p_out, unsigned* __restrict__ p_in,
                 ushort* __restrict__ rank16) {
    __shared__ unsigned bins[SLICE];   // 50 KB
    const int b = blockIdx.x;
    const bool isdst = (b >= HBLK);
    const int bb = isdst ? (b - HBLK) : b;
    const int ci = bb >> 3;            // chunk 0..31
    const int si = bb & 7;             // slice 0..7
    const int s0 = si * SLICE;

    for (int i = threadIdx.x; i < SLICE; i += 1024) bins[i] = 0;
    __syncthreads();

    const int4* ep4 = (const int4*)((isdst ? dst : src) + ci * CHUNK_E);
    if (isdst) {
        const int ebase = ci * CHUNK_E;
        for (int i = threadIdx.x; i < CHUNK_E / 4; i += 1024) {
            int4 v = ep4[i];
            int e0 = ebase + i * 4;
            unsigned u0 = (unsigned)(v.x - s0);
            unsigned u1 = (unsigned)(v.y - s0);
            unsigned u2 = (unsigned)(v.z - s0);
            unsigned u3 = (unsigned)(v.w - s0);
            if (u0 < SLICE) rank16[e0 + 0] = (ushort)atomicAdd(&bins[u0], 1u);
            if (u1 < SLICE) rank16[e0 + 1] = (ushort)atomicAdd(&bins[u1], 1u);
            if (u2 < SLICE) rank16[e0 + 2] = (ushort)atomicAdd(&bins[u2], 1u);
            if (u3 < SLICE) rank16[e0 + 3] = (ushort)atomicAdd(&bins[u3], 1u);
        }
    } else {
        for (int i = threadIdx.x; i < CHUNK_E / 4; i += 1024) {
            int4 v = ep4[i];
            unsigned u0 = (unsigned)(v.x - s0);
            unsigned u1 = (unsigned)(v.y - s0);
            unsigned u2 = (unsigned)(v.z - s0);
            unsigned u3 = (unsigned)(v.w - s0);
            if (u0 < SLICE) atomicAdd(&bins[u0], 1u);
            if (u1 < SLICE) atomicAdd(&bins[u1], 1u);
            if (u2 < SLICE) atomicAdd(&bins[u2], 1u);
            if (u3 < SLICE) atomicAdd(&bins[u3], 1u);
        }
    }
    __syncthreads();

    unsigned* pp = (isdst ? p_in : p_out) + (size_t)ci * N_NODES + s0;
    for (int i = threadIdx.x; i < SLICE; i += 1024) pp[i] = bins[i];
}

// ---------------------------------------------------------------------------
// Kernel 2: per-node: nsrc = rsqrt(max(deg_out,1)) from p_out partials;
// exclusive prefix of p_in over chunks (in place) -> deg_in.
// ---------------------------------------------------------------------------
__global__ __launch_bounds__(256)
void prefix_kernel(const unsigned* __restrict__ p_out, unsigned* __restrict__ p_in,
                   float* __restrict__ nsrc, unsigned* __restrict__ deg_in) {
    int n = blockIdx.x * 256 + threadIdx.x;
    if (n >= N_NODES) return;
    unsigned so = 0;
    #pragma unroll
    for (int c = 0; c < NCHUNK; ++c) so += p_out[(size_t)c * N_NODES + n];
    nsrc[n] = rsqrtf(fmaxf((float)so, 1.f));
    unsigned run = 0;
    #pragma unroll
    for (int c = 0; c < NCHUNK; ++c) {
        unsigned t = p_in[(size_t)c * N_NODES + n];
        p_in[(size_t)c * N_NODES + n] = run;
        run += t;
    }
    deg_in[n] = run;
}

// ---------------------------------------------------------------------------
// Kernel 3: W / skipW -> bf16 MFMA B-fragment-major; + params table
// params[col] = {b, gamma, beta, skip_b}
// ---------------------------------------------------------------------------
__global__ void wcvt_kernel(const float* __restrict__ W, const float* __restrict__ sW,
                            const float* __restrict__ bvec, const float* __restrict__ gamma,
                            const float* __restrict__ beta, const float* __restrict__ skipb,
                            ushort* __restrict__ Wfrag, ushort* __restrict__ sWfrag,
                            float4* __restrict__ params) {
    int tid = blockIdx.x * blockDim.x + threadIdx.x;
    if (tid >= 8448) return;
    if (tid >= 8192) {
        int i = tid - 8192;   // 0..255
        params[i] = make_float4(bvec[i], gamma[i], beta[i], skipb[i]);
        return;
    }
    const float* srcm = (tid < 4096) ? W : sW;
    ushort* dstm = (tid < 4096) ? Wfrag : sWfrag;
    int u = tid & 4095;
    int lane = u & 63;
    int ks = (u >> 6) & 3;
    int n = u >> 8;
    int c = lane & 15, g = lane >> 4;
    int col = n * 16 + c;
    int k0 = ks * 32 + g * 8;
    ushort4 lo, hi;
    lo.x = (ushort)f2bf(srcm[(size_t)(k0 + 0) * HID_DIM + col]);
    lo.y = (ushort)f2bf(srcm[(size_t)(k0 + 1) * HID_DIM + col]);
    lo.z = (ushort)f2bf(srcm[(size_t)(k0 + 2) * HID_DIM + col]);
    lo.w = (ushort)f2bf(srcm[(size_t)(k0 + 3) * HID_DIM + col]);
    hi.x = (ushort)f2bf(srcm[(size_t)(k0 + 4) * HID_DIM + col]);
    hi.y = (ushort)f2bf(srcm[(size_t)(k0 + 5) * HID_DIM + col]);
    hi.z = (ushort)f2bf(srcm[(size_t)(k0 + 6) * HID_DIM + col]);
    hi.w = (ushort)f2bf(srcm[(size_t)(k0 + 7) * HID_DIM + col]);
    *(ushort4*)(dstm + (size_t)u * 8)     = lo;
    *(ushort4*)(dstm + (size_t)u * 8 + 4) = hi;
}

// ---------------------------------------------------------------------------
// Kernel 4: single-block exclusive scan (4 elems/thread) deg_in -> row_ptr
// ---------------------------------------------------------------------------
__global__ __launch_bounds__(1024)
void scan_kernel(const unsigned* __restrict__ deg_in, unsigned* __restrict__ row_ptr) {
    __shared__ unsigned wsum[16];
    __shared__ unsigned carry_s;
    if (threadIdx.x == 0) carry_s = 0;
    __syncthreads();
    const int lane = threadIdx.x & 63;
    const int wid  = threadIdx.x >> 6;
    for (int base = 0; base < N_NODES; base += 4096) {
        int i0 = base + threadIdx.x * 4;
        unsigned d0 = 0, d1 = 0, d2 = 0, d3 = 0;
        if (i0 < N_NODES) {
            uint4 v = *(const uint4*)(deg_in + i0);
            d0 = v.x; d1 = v.y; d2 = v.z; d3 = v.w;
        }
        unsigned t = d0 + d1 + d2 + d3;
        unsigned x = t;
        #pragma unroll
        for (int d = 1; d < 64; d <<= 1) {
            unsigned tt = __shfl_up(x, d, 64);
            if (lane >= d) x += tt;
        }
        if (lane == 63) wsum[wid] = x;
        __syncthreads();
        if (threadIdx.x == 0) {
            unsigned run = carry_s;
            #pragma unroll
            for (int w = 0; w < 16; ++w) { unsigned tmp = wsum[w]; wsum[w] = run; run += tmp; }
            carry_s = run;
        }
        __syncthreads();
        if (i0 < N_NODES) {
            unsigned b = wsum[wid] + (x - t);
            uint4 rp;
            rp.x = b; rp.y = b + d0; rp.z = b + d0 + d1; rp.w = b + d0 + d1 + d2;
            *(uint4*)(row_ptr + i0) = rp;
        }
        __syncthreads();
    }
    if (threadIdx.x == 0) row_ptr[N_NODES] = carry_s;
}

// ---------------------------------------------------------------------------
// Kernel 5 (pre2), fused by block range:
//   [0, 6250)       : atomic-free CSR fill via chunk-prefix + within-chunk rank
//   [6250, 18750)   : featb = bf16(feat)   (UNscaled; spmm applies nsrc)
// ---------------------------------------------------------------------------
__global__ __launch_bounds__(256)
void pre2_kernel(const int* __restrict__ src, const int* __restrict__ dst,
                 const unsigned* __restrict__ row_ptr, const unsigned* __restrict__ p_in,
                 const ushort* __restrict__ rank16, unsigned* __restrict__ edge_src,
                 const float* __restrict__ feat, ushort* __restrict__ featb) {
    const int b = blockIdx.x;
    if (b < EDGE_BLOCKS) {
        int e = b * 256 + threadIdx.x;
        int d = dst[e];
        int c = e / CHUNK_E;
        unsigned pos = row_ptr[d] + p_in[(size_t)c * N_NODES + d] + (unsigned)rank16[e];
        edge_src[pos] = (unsigned)src[e];
    } else {
        int id = (b - EDGE_BLOCKS) * 256 + threadIdx.x;   // exact N_NODES*32
        float4 v = ((const float4*)feat)[id];
        ushort4 o;
        o.x = (ushort)f2bf(v.x);
        o.y = (ushort)f2bf(v.y);
        o.z = (ushort)f2bf(v.z);
        o.w = (ushort)f2bf(v.w);
        ((ushort4*)featb)[id] = o;
    }
}

// ---------------------------------------------------------------------------
// Kernel 6: row-per-wave gather SpMM over bf16 featb, scale by nsrc[s] -> aggb
// ---------------------------------------------------------------------------
__global__ __launch_bounds__(256)
void spmm_kernel(const ushort* __restrict__ featb, const float* __restrict__ nsrc,
                 const unsigned* __restrict__ row_ptr, const unsigned* __restrict__ edge_src,
                 unsigned* __restrict__ aggb_u32) {
    int gw = (blockIdx.x * 256 + threadIdx.x) >> 6;
    int lane = threadIdx.x & 63;
    if (gw >= N_NODES) return;
    unsigned beg = row_ptr[gw], end = row_ptr[gw + 1];
    float a0 = 0.f, a1 = 0.f;
    unsigned e = beg;
    for (; e + 4 <= end; e += 4) {
        unsigned s0 = edge_src[e + 0];
        unsigned s1 = edge_src[e + 1];
        unsigned s2 = edge_src[e + 2];
        unsigned s3 = edge_src[e + 3];
        float n0 = nsrc[s0], n1 = nsrc[s1], n2 = nsrc[s2], n3 = nsrc[s3];
        unsigned v0 = *(const unsigned*)(featb + (size_t)s0 * IN_DIM + 2 * lane);
        unsigned v1 = *(const unsigned*)(featb + (size_t)s1 * IN_DIM + 2 * lane);
        unsigned v2 = *(const unsigned*)(featb + (size_t)s2 * IN_DIM + 2 * lane);
        unsigned v3 = *(const unsigned*)(featb + (size_t)s3 * IN_DIM + 2 * lane);
        a0 = fmaf(bf2f_lo(v0), n0, a0); a1 = fmaf(bf2f_hi(v0), n0, a1);
        a0 = fmaf(bf2f_lo(v1), n1, a0); a1 = fmaf(bf2f_hi(v1), n1, a1);
        a0 = fmaf(bf2f_lo(v2), n2, a0); a1 = fmaf(bf2f_hi(v2), n2, a1);
        a0 = fmaf(bf2f_lo(v3), n3, a0); a1 = fmaf(bf2f_hi(v3), n3, a1);
    }
    for (; e < end; ++e) {
        unsigned s = edge_src[e];
        float ns = nsrc[s];
        unsigned v = *(const unsigned*)(featb + (size_t)s * IN_DIM + 2 * lane);
        a0 = fmaf(bf2f_lo(v), ns, a0); a1 = fmaf(bf2f_hi(v), ns, a1);
    }
    float nd = rsqrtf(fmaxf((float)(end - beg), 1.0f));
    unsigned lo = (unsigned)(ushort)f2bf(a0 * nd);
    unsigned hi = (unsigned)(ushort)f2bf(a1 * nd);
    aggb_u32[(size_t)gw * (IN_DIM / 2) + lane] = lo | (hi << 16);
}

// ---------------------------------------------------------------------------
// Kernel 7: FUSED GEMM1 + LN + ReLU + GEMM2 + biases -> out, v4 (r3 revival).
// NO LDS, NO barriers, NO loop: 3125 blocks x 128 threads = 6250 waves,
// exactly one 16-row tile per wave. B streamed from global in fragment-major
// order (1 KB contiguous per wave-load, L2/L3-hot). A2 = direct bf16 load.
// Params from 4 KB global table (L1-hot) instead of 64 resident VGPRs.
// Live set ~100 VGPRs -> no spill, 4+ blocks/CU.
// ---------------------------------------------------------------------------
__global__ __launch_bounds__(128)
void gemm_fused_kernel(const ushort* __restrict__ aggb, const ushort* __restrict__ featb,
                       const ushort* __restrict__ Wfrag, const ushort* __restrict__ sWfrag,
                       const float4* __restrict__ params, float* __restrict__ out) {
    const int tid = threadIdx.x;
    const int lane = tid & 63;
    const int c = lane & 15, g = lane >> 4;
    const int t = blockIdx.x * 2 + (tid >> 6);   // tile 0..6249, exact
    const int r0 = t * 16;

    // ---- GEMM 1: aggb @ W + b ----------------------------------------------
    bf16x8 A[4];
    #pragma unroll
    for (int ks = 0; ks < 4; ++ks)
        A[ks] = *(const bf16x8*)(aggb + (size_t)(r0 + c) * IN_DIM + ks * 32 + g * 8);

    f32x4 acc[16];
    #pragma unroll
    for (int n = 0; n < 16; ++n) {
        float bb = params[n * 16 + c].x;
        acc[n] = (f32x4){bb, bb, bb, bb};
        #pragma unroll
        for (int ks = 0; ks < 4; ++ks) {
            bf16x8 b = *(const bf16x8*)(Wfrag + ((n * 4 + ks) * 64 + lane) * 8);
            acc[n] = __builtin_amdgcn_mfma_f32_16x16x32_bf16(A[ks], b, acc[n], 0, 0, 0);
        }
    }

    // ---- A2: direct bf16 load (issued before LN; latency hides under it) --
    #pragma unroll
    for (int ks = 0; ks < 4; ++ks)
        A[ks] = *(const bf16x8*)(featb + (size_t)(r0 + c) * IN_DIM + ks * 32 + g * 8);

    // ---- in-wave LayerNorm stats -------------------------------------------
    float mu[4], rstd[4];
    {
        float s1[4], s2[4];
        #pragma unroll
        for (int j = 0; j < 4; ++j) { s1[j] = 0.f; s2[j] = 0.f; }
        #pragma unroll
        for (int n = 0; n < 16; ++n) {
            #pragma unroll
            for (int j = 0; j < 4; ++j) {
                s1[j] += acc[n][j];
                s2[j] = fmaf(acc[n][j], acc[n][j], s2[j]);
            }
        }
        #pragma unroll
        for (int m = 1; m <= 8; m <<= 1) {
            #pragma unroll
            for (int j = 0; j < 4; ++j) {
                s1[j] += __shfl_xor(s1[j], m, 64);
                s2[j] += __shfl_xor(s2[j], m, 64);
            }
        }
        #pragma unroll
        for (int j = 0; j < 4; ++j) {
            mu[j] = s1[j] * (1.f / HID_DIM);
            float var = s2[j] * (1.f / HID_DIM) - mu[j] * mu[j];
            rstd[j] = rsqrtf(var + LN_EPS);
        }
    }

    // ---- LN apply + ReLU + skip_b ------------------------------------------
    #pragma unroll
    for (int n = 0; n < 16; ++n) {
        float4 p = params[n * 16 + c];   // {b, gamma, beta, skipb}
        #pragma unroll
        for (int j = 0; j < 4; ++j)
            acc[n][j] = fmaxf(fmaf((acc[n][j] - mu[j]) * rstd[j], p.y, p.z), 0.f) + p.w;
    }

    // ---- GEMM 2: + feat @ skipW --------------------------------------------
    #pragma unroll
    for (int n = 0; n < 16; ++n) {
        #pragma unroll
        for (int ks = 0; ks < 4; ++ks) {
            bf16x8 b = *(const bf16x8*)(sWfrag + ((n * 4 + ks) * 64 + lane) * 8);
            acc[n] = __builtin_amdgcn_mfma_f32_16x16x32_bf16(A[ks], b, acc[n], 0, 0, 0);
        }
    }

    // ---- store out (f32 row-major) -----------------------------------------
    #pragma unroll
    for (int n = 0; n < 16; ++n) {
        #pragma unroll
        for (int j = 0; j < 4; ++j)
            out[(size_t)(r0 + g * 4 + j) * HID_DIM + n * 16 + c] = acc[n][j];
    }
}

// ---------------------------------------------------------------------------
extern "C" void kernel_launch(void* const* d_in, const int* in_sizes, int n_in,
                              void* d_out, int out_size, void* d_ws, size_t ws_size,
                              hipStream_t stream) {
    const float* feat  = (const float*)d_in[0];
    const int*   src   = (const int*)d_in[1];
    const int*   dst   = (const int*)d_in[2];
    const float* W     = (const float*)d_in[3];
    const float* bvec  = (const float*)d_in[4];
    const float* gamma = (const float*)d_in[5];
    const float* beta  = (const float*)d_in[6];
    const float* skipW = (const float*)d_in[7];
    const float* skipb = (const float*)d_in[8];
    float* out = (float*)d_out;

    // workspace, peak ≈ 77 MB:
    // [Wfrag 64K][sWfrag 64K][params 4K][aggb 25.6M][featb 25.6M (p_out 12.8M
    //  aliases it; dead before pre2 writes featb) | edge_src 6.4M |
    //  rank16 3.2M | p_in 12.8M | nsrc .4 | deg_in .4 | row_ptr .4]
    char* ws = (char*)d_ws;
    ushort*   Wfrag    = (ushort*)ws;                               // 64 KB
    ushort*   sWfrag   = Wfrag + 32768;                             // 64 KB
    float4*   params   = (float4*)(sWfrag + 32768);                 // 4 KB
    ushort*   aggb     = (ushort*)(params + 256);                   // 25.6 MB
    char*     xbase    = (char*)(aggb + (size_t)N_NODES * IN_DIM);
    ushort*   featb    = (ushort*)xbase;                            // 25.6 MB
    unsigned* p_out    = (unsigned*)xbase;                          // 12.8 MB (alias featb)
    unsigned* edge_src = (unsigned*)(featb + (size_t)N_NODES * IN_DIM); // 6.4 MB
    ushort*   rank16   = (ushort*)(edge_src + N_EDGES);             // 3.2 MB
    unsigned* p_in     = (unsigned*)(rank16 + N_EDGES);             // 12.8 MB
    float*    nsrc     = (float*)(p_in + (size_t)NCHUNK * N_NODES); // 400 KB
    unsigned* deg_in   = (unsigned*)(nsrc + N_NODES);               // 400 KB
    unsigned* row_ptr  = deg_in + N_NODES;                          // 400 KB + pad

    wcvt_kernel<<<33, 256, 0, stream>>>(W, skipW, bvec, gamma, beta, skipb,
                                        Wfrag, sWfrag, params);

    hist_kernel<<<2 * HBLK, 1024, 0, stream>>>(src, dst, p_out, p_in, rank16);

    prefix_kernel<<<(N_NODES + 255) / 256, 256, 0, stream>>>(p_out, p_in, nsrc, deg_in);

    scan_kernel<<<1, 1024, 0, stream>>>(deg_in, row_ptr);

    pre2_kernel<<<EDGE_BLOCKS + FCVT_BLOCKS, 256, 0, stream>>>(
        src, dst, row_ptr, p_in, rank16, edge_src, feat, featb);

    spmm_kernel<<<(N_NODES * 64 + 255) / 256, 256, 0, stream>>>(featb, nsrc, row_ptr,
                                                                edge_src, (unsigned*)aggb);

    gemm_fused_kernel<<<NT / 2, 128, 0, stream>>>(
        aggb, featb, Wfrag, sWfrag, params, out);
}

// Round 14
// 234.594 us; speedup vs baseline: 2.8727x; 1.2454x over previous
//
#include <hip/hip_runtime.h>
#include <hip/hip_bf16.h>

#define N_NODES 100000
#define N_EDGES 1600000
#define IN_DIM 128
#define HID_DIM 256
#define LN_EPS 1e-5f
#define NT (N_NODES / 16)   // 6250 16-row tiles, exact

// histogram geometry
#define NCHUNK 32
#define CHUNK_E (N_EDGES / NCHUNK)     // 50000 edges/chunk (12500 int4, exact)
#define NSLICE 8
#define SLICE (N_NODES / NSLICE)       // 12500 nodes/slice (50 KB LDS bins)
#define HBLK (NCHUNK * NSLICE)         // 256 blocks per histogrammed array

#define EDGE_BLOCKS (N_EDGES / 256)       // 6250, exact
#define FCVT_BLOCKS (N_NODES * 32 / 256)  // 12500, exact

typedef short bf16x8 __attribute__((ext_vector_type(8)));
typedef float f32x4  __attribute__((ext_vector_type(4)));

static __device__ __forceinline__ short f2bf(float x) {
    return __builtin_bit_cast(short, __float2bfloat16(x));  // RNE round
}
static __device__ __forceinline__ float bf2f_lo(unsigned v) {
    return __builtin_bit_cast(float, v << 16);
}
static __device__ __forceinline__ float bf2f_hi(unsigned v) {
    return __builtin_bit_cast(float, v & 0xffff0000u);
}

// ---------------------------------------------------------------------------
// Kernel 1: LDS-bin histograms — NO global atomics.
//   blocks [0, 256)   : histogram of src  -> p_out[chunk][node]
//   blocks [256, 512) : histogram of dst  -> p_in[chunk][node], and the LDS
//                       atomic's return value = within-chunk rank -> rank16[e]
// ---------------------------------------------------------------------------
__global__ __launch_bounds__(1024)
void hist_kernel(const int* __restrict__ src, const int* __restrict__ dst,
                 unsigned* __restrict__ p_out, unsigned* __restrict__ p_in,
                 ushort* __restrict__ rank16) {
    __shared__ unsigned bins[SLICE];   // 50 KB
    const int b = blockIdx.x;
    const bool isdst = (b >= HBLK);
    const int bb = isdst ? (b - HBLK) : b;
    const int ci = bb >> 3;            // chunk 0..31
    const int si = bb & 7;             // slice 0..7
    const int s0 = si * SLICE;

    for (int i = threadIdx.x; i < SLICE; i += 1024) bins[i] = 0;
    __syncthreads();

    const int4* ep4 = (const int4*)((isdst ? dst : src) + ci * CHUNK_E);
    if (isdst) {
        const int ebase = ci * CHUNK_E;
        for (int i = threadIdx.x; i < CHUNK_E / 4; i += 1024) {
            int4 v = ep4[i];
            int e0 = ebase + i * 4;
            unsigned u0 = (unsigned)(v.x - s0);
            unsigned u1 = (unsigned)(v.y - s0);
            unsigned u2 = (unsigned)(v.z - s0);
            unsigned u3 = (unsigned)(v.w - s0);
            if (u0 < SLICE) rank16[e0 + 0] = (ushort)atomicAdd(&bins[u0], 1u);
            if (u1 < SLICE) rank16[e0 + 1] = (ushort)atomicAdd(&bins[u1], 1u);
            if (u2 < SLICE) rank16[e0 + 2] = (ushort)atomicAdd(&bins[u2], 1u);
            if (u3 < SLICE) rank16[e0 + 3] = (ushort)atomicAdd(&bins[u3], 1u);
        }
    } else {
        for (int i = threadIdx.x; i < CHUNK_E / 4; i += 1024) {
            int4 v = ep4[i];
            unsigned u0 = (unsigned)(v.x - s0);
            unsigned u1 = (unsigned)(v.y - s0);
            unsigned u2 = (unsigned)(v.z - s0);
            unsigned u3 = (unsigned)(v.w - s0);
            if (u0 < SLICE) atomicAdd(&bins[u0], 1u);
            if (u1 < SLICE) atomicAdd(&bins[u1], 1u);
            if (u2 < SLICE) atomicAdd(&bins[u2], 1u);
            if (u3 < SLICE) atomicAdd(&bins[u3], 1u);
        }
    }
    __syncthreads();

    unsigned* pp = (isdst ? p_in : p_out) + (size_t)ci * N_NODES + s0;
    for (int i = threadIdx.x; i < SLICE; i += 1024) pp[i] = bins[i];
}

// ---------------------------------------------------------------------------
// Kernel 2: per-node: nsrc = rsqrt(max(deg_out,1)) from p_out partials;
// exclusive prefix of p_in over chunks (in place) -> deg_in.
// ---------------------------------------------------------------------------
__global__ __launch_bounds__(256)
void prefix_kernel(const unsigned* __restrict__ p_out, unsigned* __restrict__ p_in,
                   float* __restrict__ nsrc, unsigned* __restrict__ deg_in) {
    int n = blockIdx.x * 256 + threadIdx.x;
    if (n >= N_NODES) return;
    unsigned so = 0;
    #pragma unroll
    for (int c = 0; c < NCHUNK; ++c) so += p_out[(size_t)c * N_NODES + n];
    nsrc[n] = rsqrtf(fmaxf((float)so, 1.f));
    unsigned run = 0;
    #pragma unroll
    for (int c = 0; c < NCHUNK; ++c) {
        unsigned t = p_in[(size_t)c * N_NODES + n];
        p_in[(size_t)c * N_NODES + n] = run;
        run += t;
    }
    deg_in[n] = run;
}

// ---------------------------------------------------------------------------
// Kernel 3: W / skipW -> bf16 MFMA B-fragment-major; + params table
// params[col] = {b, gamma, beta, skip_b}
// ---------------------------------------------------------------------------
__global__ void wcvt_kernel(const float* __restrict__ W, const float* __restrict__ sW,
                            const float* __restrict__ bvec, const float* __restrict__ gamma,
                            const float* __restrict__ beta, const float* __restrict__ skipb,
                            ushort* __restrict__ Wfrag, ushort* __restrict__ sWfrag,
                            float4* __restrict__ params) {
    int tid = blockIdx.x * blockDim.x + threadIdx.x;
    if (tid >= 8448) return;
    if (tid >= 8192) {
        int i = tid - 8192;   // 0..255
        params[i] = make_float4(bvec[i], gamma[i], beta[i], skipb[i]);
        return;
    }
    const float* srcm = (tid < 4096) ? W : sW;
    ushort* dstm = (tid < 4096) ? Wfrag : sWfrag;
    int u = tid & 4095;
    int lane = u & 63;
    int ks = (u >> 6) & 3;
    int n = u >> 8;
    int c = lane & 15, g = lane >> 4;
    int col = n * 16 + c;
    int k0 = ks * 32 + g * 8;
    ushort4 lo, hi;
    lo.x = (ushort)f2bf(srcm[(size_t)(k0 + 0) * HID_DIM + col]);
    lo.y = (ushort)f2bf(srcm[(size_t)(k0 + 1) * HID_DIM + col]);
    lo.z = (ushort)f2bf(srcm[(size_t)(k0 + 2) * HID_DIM + col]);
    lo.w = (ushort)f2bf(srcm[(size_t)(k0 + 3) * HID_DIM + col]);
    hi.x = (ushort)f2bf(srcm[(size_t)(k0 + 4) * HID_DIM + col]);
    hi.y = (ushort)f2bf(srcm[(size_t)(k0 + 5) * HID_DIM + col]);
    hi.z = (ushort)f2bf(srcm[(size_t)(k0 + 6) * HID_DIM + col]);
    hi.w = (ushort)f2bf(srcm[(size_t)(k0 + 7) * HID_DIM + col]);
    *(ushort4*)(dstm + (size_t)u * 8)     = lo;
    *(ushort4*)(dstm + (size_t)u * 8 + 4) = hi;
}

// ---------------------------------------------------------------------------
// Kernel 4: single-block exclusive scan (4 elems/thread) deg_in -> row_ptr
// ---------------------------------------------------------------------------
__global__ __launch_bounds__(1024)
void scan_kernel(const unsigned* __restrict__ deg_in, unsigned* __restrict__ row_ptr) {
    __shared__ unsigned wsum[16];
    __shared__ unsigned carry_s;
    if (threadIdx.x == 0) carry_s = 0;
    __syncthreads();
    const int lane = threadIdx.x & 63;
    const int wid  = threadIdx.x >> 6;
    for (int base = 0; base < N_NODES; base += 4096) {
        int i0 = base + threadIdx.x * 4;
        unsigned d0 = 0, d1 = 0, d2 = 0, d3 = 0;
        if (i0 < N_NODES) {
            uint4 v = *(const uint4*)(deg_in + i0);
            d0 = v.x; d1 = v.y; d2 = v.z; d3 = v.w;
        }
        unsigned t = d0 + d1 + d2 + d3;
        unsigned x = t;
        #pragma unroll
        for (int d = 1; d < 64; d <<= 1) {
            unsigned tt = __shfl_up(x, d, 64);
            if (lane >= d) x += tt;
        }
        if (lane == 63) wsum[wid] = x;
        __syncthreads();
        if (threadIdx.x == 0) {
            unsigned run = carry_s;
            #pragma unroll
            for (int w = 0; w < 16; ++w) { unsigned tmp = wsum[w]; wsum[w] = run; run += tmp; }
            carry_s = run;
        }
        __syncthreads();
        if (i0 < N_NODES) {
            unsigned b = wsum[wid] + (x - t);
            uint4 rp;
            rp.x = b; rp.y = b + d0; rp.z = b + d0 + d1; rp.w = b + d0 + d1 + d2;
            *(uint4*)(row_ptr + i0) = rp;
        }
        __syncthreads();
    }
    if (threadIdx.x == 0) row_ptr[N_NODES] = carry_s;
}

// ---------------------------------------------------------------------------
// Kernel 5 (pre2), fused by block range:
//   [0, 6250)       : atomic-free CSR fill via chunk-prefix + within-chunk rank
//   [6250, 18750)   : featb = bf16(feat)   (UNscaled; spmm applies nsrc)
// ---------------------------------------------------------------------------
__global__ __launch_bounds__(256)
void pre2_kernel(const int* __restrict__ src, const int* __restrict__ dst,
                 const unsigned* __restrict__ row_ptr, const unsigned* __restrict__ p_in,
                 const ushort* __restrict__ rank16, unsigned* __restrict__ edge_src,
                 const float* __restrict__ feat, ushort* __restrict__ featb) {
    const int b = blockIdx.x;
    if (b < EDGE_BLOCKS) {
        int e = b * 256 + threadIdx.x;
        int d = dst[e];
        int c = e / CHUNK_E;
        unsigned pos = row_ptr[d] + p_in[(size_t)c * N_NODES + d] + (unsigned)rank16[e];
        edge_src[pos] = (unsigned)src[e];
    } else {
        int id = (b - EDGE_BLOCKS) * 256 + threadIdx.x;   // exact N_NODES*32
        float4 v = ((const float4*)feat)[id];
        ushort4 o;
        o.x = (ushort)f2bf(v.x);
        o.y = (ushort)f2bf(v.y);
        o.z = (ushort)f2bf(v.z);
        o.w = (ushort)f2bf(v.w);
        ((ushort4*)featb)[id] = o;
    }
}

// ---------------------------------------------------------------------------
// Kernel 6: row-per-wave gather SpMM over bf16 featb, scale by nsrc[s] -> aggb
// 8-deep unroll: 8 edge_src + 8 nsrc + 8 row loads in flight per wave.
// ---------------------------------------------------------------------------
__global__ __launch_bounds__(256)
void spmm_kernel(const ushort* __restrict__ featb, const float* __restrict__ nsrc,
                 const unsigned* __restrict__ row_ptr, const unsigned* __restrict__ edge_src,
                 unsigned* __restrict__ aggb_u32) {
    int gw = (blockIdx.x * 256 + threadIdx.x) >> 6;
    int lane = threadIdx.x & 63;
    if (gw >= N_NODES) return;
    unsigned beg = row_ptr[gw], end = row_ptr[gw + 1];
    float a0 = 0.f, a1 = 0.f;
    unsigned e = beg;
    for (; e + 8 <= end; e += 8) {
        unsigned s[8];
        #pragma unroll
        for (int q = 0; q < 8; ++q) s[q] = edge_src[e + q];
        float ns[8];
        #pragma unroll
        for (int q = 0; q < 8; ++q) ns[q] = nsrc[s[q]];
        unsigned v[8];
        #pragma unroll
        for (int q = 0; q < 8; ++q)
            v[q] = *(const unsigned*)(featb + (size_t)s[q] * IN_DIM + 2 * lane);
        #pragma unroll
        for (int q = 0; q < 8; ++q) {
            a0 = fmaf(bf2f_lo(v[q]), ns[q], a0);
            a1 = fmaf(bf2f_hi(v[q]), ns[q], a1);
        }
    }
    for (; e < end; ++e) {
        unsigned s = edge_src[e];
        float ns = nsrc[s];
        unsigned v = *(const unsigned*)(featb + (size_t)s * IN_DIM + 2 * lane);
        a0 = fmaf(bf2f_lo(v), ns, a0); a1 = fmaf(bf2f_hi(v), ns, a1);
    }
    float nd = rsqrtf(fmaxf((float)(end - beg), 1.0f));
    unsigned lo = (unsigned)(ushort)f2bf(a0 * nd);
    unsigned hi = (unsigned)(ushort)f2bf(a1 * nd);
    aggb_u32[(size_t)gw * (IN_DIM / 2) + lane] = lo | (hi << 16);
}

// ---------------------------------------------------------------------------
// Kernel 7: FUSED GEMM1 + LN + ReLU + GEMM2 -> out, v5 (col-split).
// 2 waves per 16-row tile: wave h owns cols [h*128, h*128+128) (n in [8h,8h+8)).
// acc = 32 VGPRs, per-wave chain = 64 MFMAs + ~70 loads (half of v4) ->
// live set ~100 VGPRs -> 4-5 waves/SIMD. LN: in-wave partials + one tiny
// LDS combine (64 B, one barrier, single-shot). NO weight LDS (B streamed
// fragment-major from L2, empirically fastest). 3125 blocks x 256.
// ---------------------------------------------------------------------------
__global__ __launch_bounds__(256)
void gemm_fused_kernel(const ushort* __restrict__ aggb, const ushort* __restrict__ featb,
                       const ushort* __restrict__ Wfrag, const ushort* __restrict__ sWfrag,
                       const float4* __restrict__ params, float* __restrict__ out) {
    __shared__ float2 red[2][2][16];   // [tile-in-block][col-half][row]: (s1,s2)
    const int tid = threadIdx.x;
    const int lane = tid & 63;
    const int wv = tid >> 6;           // wave 0..3
    const int tb = wv >> 1;            // tile-in-block 0..1
    const int h  = wv & 1;             // col-half 0..1
    const int c = lane & 15, g = lane >> 4;
    const int t = blockIdx.x * 2 + tb; // tile 0..6249, exact
    const int r0 = t * 16;
    const int n0 = h * 8;

    // ---- GEMM 1: aggb @ W + b (this wave's 128 cols) -----------------------
    bf16x8 A[4];
    #pragma unroll
    for (int ks = 0; ks < 4; ++ks)
        A[ks] = *(const bf16x8*)(aggb + (size_t)(r0 + c) * IN_DIM + ks * 32 + g * 8);

    f32x4 acc[8];
    #pragma unroll
    for (int i = 0; i < 8; ++i) {
        const int n = n0 + i;
        float bb = params[n * 16 + c].x;
        acc[i] = (f32x4){bb, bb, bb, bb};
        #pragma unroll
        for (int ks = 0; ks < 4; ++ks) {
            bf16x8 b = *(const bf16x8*)(Wfrag + ((n * 4 + ks) * 64 + lane) * 8);
            acc[i] = __builtin_amdgcn_mfma_f32_16x16x32_bf16(A[ks], b, acc[i], 0, 0, 0);
        }
    }

    // ---- A2: direct bf16 load, issued before LN (latency hides under it) --
    #pragma unroll
    for (int ks = 0; ks < 4; ++ks)
        A[ks] = *(const bf16x8*)(featb + (size_t)(r0 + c) * IN_DIM + ks * 32 + g * 8);

    // ---- LN partials over this wave's 128 cols -----------------------------
    float s1[4], s2[4];
    #pragma unroll
    for (int j = 0; j < 4; ++j) { s1[j] = 0.f; s2[j] = 0.f; }
    #pragma unroll
    for (int i = 0; i < 8; ++i) {
        #pragma unroll
        for (int j = 0; j < 4; ++j) {
            s1[j] += acc[i][j];
            s2[j] = fmaf(acc[i][j], acc[i][j], s2[j]);
        }
    }
    #pragma unroll
    for (int m = 1; m <= 8; m <<= 1) {
        #pragma unroll
        for (int j = 0; j < 4; ++j) {
            s1[j] += __shfl_xor(s1[j], m, 64);
            s2[j] += __shfl_xor(s2[j], m, 64);
        }
    }
    if (c == 0) {
        #pragma unroll
        for (int j = 0; j < 4; ++j)
            red[tb][h][g * 4 + j] = make_float2(s1[j], s2[j]);
    }
    __syncthreads();

    // ---- combine halves -> mu, rstd ----------------------------------------
    float mu[4], rstd[4];
    #pragma unroll
    for (int j = 0; j < 4; ++j) {
        float2 p0 = red[tb][0][g * 4 + j];
        float2 p1 = red[tb][1][g * 4 + j];
        float t1 = p0.x + p1.x;
        float t2 = p0.y + p1.y;
        mu[j] = t1 * (1.f / HID_DIM);
        float var = t2 * (1.f / HID_DIM) - mu[j] * mu[j];
        rstd[j] = rsqrtf(var + LN_EPS);
    }

    // ---- LN apply + ReLU + skip_b ------------------------------------------
    #pragma unroll
    for (int i = 0; i < 8; ++i) {
        float4 p = params[(n0 + i) * 16 + c];   // {b, gamma, beta, skipb}
        #pragma unroll
        for (int j = 0; j < 4; ++j)
            acc[i][j] = fmaxf(fmaf((acc[i][j] - mu[j]) * rstd[j], p.y, p.z), 0.f) + p.w;
    }

    // ---- GEMM 2: + feat @ skipW --------------------------------------------
    #pragma unroll
    for (int i = 0; i < 8; ++i) {
        const int n = n0 + i;
        #pragma unroll
        for (int ks = 0; ks < 4; ++ks) {
            bf16x8 b = *(const bf16x8*)(sWfrag + ((n * 4 + ks) * 64 + lane) * 8);
            acc[i] = __builtin_amdgcn_mfma_f32_16x16x32_bf16(A[ks], b, acc[i], 0, 0, 0);
        }
    }

    // ---- store out (f32 row-major, this wave's 128 cols) -------------------
    #pragma unroll
    for (int i = 0; i < 8; ++i) {
        #pragma unroll
        for (int j = 0; j < 4; ++j)
            out[(size_t)(r0 + g * 4 + j) * HID_DIM + (n0 + i) * 16 + c] = acc[i][j];
    }
}

// ---------------------------------------------------------------------------
extern "C" void kernel_launch(void* const* d_in, const int* in_sizes, int n_in,
                              void* d_out, int out_size, void* d_ws, size_t ws_size,
                              hipStream_t stream) {
    const float* feat  = (const float*)d_in[0];
    const int*   src   = (const int*)d_in[1];
    const int*   dst   = (const int*)d_in[2];
    const float* W     = (const float*)d_in[3];
    const float* bvec  = (const float*)d_in[4];
    const float* gamma = (const float*)d_in[5];
    const float* beta  = (const float*)d_in[6];
    const float* skipW = (const float*)d_in[7];
    const float* skipb = (const float*)d_in[8];
    float* out = (float*)d_out;

    // workspace, peak ≈ 77 MB:
    // [Wfrag 64K][sWfrag 64K][params 4K][aggb 25.6M][featb 25.6M (p_out 12.8M
    //  aliases it; dead before pre2 writes featb) | edge_src 6.4M |
    //  rank16 3.2M | p_in 12.8M | nsrc .4 | deg_in .4 | row_ptr .4]
    char* ws = (char*)d_ws;
    ushort*   Wfrag    = (ushort*)ws;                               // 64 KB
    ushort*   sWfrag   = Wfrag + 32768;                             // 64 KB
    float4*   params   = (float4*)(sWfrag + 32768);                 // 4 KB
    ushort*   aggb     = (ushort*)(params + 256);                   // 25.6 MB
    char*     xbase    = (char*)(aggb + (size_t)N_NODES * IN_DIM);
    ushort*   featb    = (ushort*)xbase;                            // 25.6 MB
    unsigned* p_out    = (unsigned*)xbase;                          // 12.8 MB (alias featb)
    unsigned* edge_src = (unsigned*)(featb + (size_t)N_NODES * IN_DIM); // 6.4 MB
    ushort*   rank16   = (ushort*)(edge_src + N_EDGES);             // 3.2 MB
    unsigned* p_in     = (unsigned*)(rank16 + N_EDGES);             // 12.8 MB
    float*    nsrc     = (float*)(p_in + (size_t)NCHUNK * N_NODES); // 400 KB
    unsigned* deg_in   = (unsigned*)(nsrc + N_NODES);               // 400 KB
    unsigned* row_ptr  = deg_in + N_NODES;                          // 400 KB + pad

    wcvt_kernel<<<33, 256, 0, stream>>>(W, skipW, bvec, gamma, beta, skipb,
                                        Wfrag, sWfrag, params);

    hist_kernel<<<2 * HBLK, 1024, 0, stream>>>(src, dst, p_out, p_in, rank16);

    prefix_kernel<<<(N_NODES + 255) / 256, 256, 0, stream>>>(p_out, p_in, nsrc, deg_in);

    scan_kernel<<<1, 1024, 0, stream>>>(deg_in, row_ptr);

    pre2_kernel<<<EDGE_BLOCKS + FCVT_BLOCKS, 256, 0, stream>>>(
        src, dst, row_ptr, p_in, rank16, edge_src, feat, featb);

    spmm_kernel<<<(N_NODES * 64 + 255) / 256, 256, 0, stream>>>(featb, nsrc, row_ptr,
                                                                edge_src, (unsigned*)aggb);

    gemm_fused_kernel<<<NT / 2, 256, 0, stream>>>(
        aggb, featb, Wfrag, sWfrag, params, out);
}